// Round 21
// baseline (639.018 us; speedup 1.0000x reference)
//
#include <hip/hip_runtime.h>
#include <hip/hip_bf16.h>
#include <cstdint>
#include <math.h>

// ---------------------------------------------------------------------------
// AdaptiveMCTSReasoner  B=16, S=1024, H=1024, MAX_SIMS=100, K_FOCUS=3
// Round 21: R20 +
//  - gemm_bt: 3-buffer LDS + counted vmcnt (T4): wait vmcnt(3) -> raw
//    s_barrier -> stage(it+2) -> compute(it). Each stage gets TWO compute
//    phases to land (was one + full drain). G=3 glls/thread/stage verified
//    by static_assert for all instantiations.
//  - accinit also writes acc_bf; post-corrections reconvert of touched rows
//    only (idempotent) replaces the full cvt pass. Bit-identical.
// Selection path byte-identical to rounds 5-20 (passing, absmax 0.5).
// ---------------------------------------------------------------------------

#define SEQ 1024
#define BATCH 16
#define HDIM 1024
#define NSIM 100
#define NCHAIN (NSIM * BATCH)   // 1600
#define NCH3 (3 * NCHAIN)       // 4800
#define SHC (SEQ * HDIM)

typedef short bf16x8 __attribute__((ext_vector_type(8)));
typedef float f32x4 __attribute__((ext_vector_type(4)));
typedef float float4v __attribute__((ext_vector_type(4)));

__device__ __forceinline__ unsigned short f2bf(float f) {
    union { float f; uint32_t u; } c; c.f = f;
    uint32_t u = c.u;
    return (unsigned short)((u + 0x7FFFu + ((u >> 16) & 1u)) >> 16);   // RNE
}
__device__ __forceinline__ float bf2f(unsigned short h) {
    union { uint32_t u; float f; } c; c.u = ((uint32_t)h) << 16;
    return c.f;
}

__device__ __forceinline__ void gll16(const void* g, void* l) {
    __builtin_amdgcn_global_load_lds(
        (const __attribute__((address_space(1))) void*)g,
        (__attribute__((address_space(3))) void*)l, 16, 0, 0);
}

__device__ __forceinline__ float gelu32(float x) {
    return 0.5f * x * (1.0f + erff(x * 0.70710678f));
}

// XCD-aware bijective swizzle (requires nwg % 8 == 0; all our grids qualify)
__device__ __forceinline__ void swz_block(int& bx, int& by) {
    int gx = gridDim.x;
    int h = blockIdx.y * gx + blockIdx.x;
    int nwg = gx * gridDim.y;
    int l = (h & 7) * (nwg >> 3) + (h >> 3);
    bx = l % gx; by = l / gx;
}

// ------------------------------- threefry ----------------------------------
__device__ __forceinline__ uint32_t rotl32(uint32_t v, int r) {
    return (v << r) | (v >> (32 - r));
}

__device__ __forceinline__ void threefry(uint32_t k0, uint32_t k1,
                                         uint32_t c0, uint32_t c1,
                                         uint32_t& o0, uint32_t& o1) {
    uint32_t ks0 = k0, ks1 = k1, ks2 = k0 ^ k1 ^ 0x1BD11BDAu;
    uint32_t x0 = c0 + ks0, x1 = c1 + ks1;
#define TFR(r) { x0 += x1; x1 = rotl32(x1, r); x1 ^= x0; }
    TFR(13) TFR(15) TFR(26) TFR(6)   x0 += ks1; x1 += ks2 + 1u;
    TFR(17) TFR(29) TFR(16) TFR(24)  x0 += ks2; x1 += ks0 + 2u;
    TFR(13) TFR(15) TFR(26) TFR(6)   x0 += ks0; x1 += ks1 + 3u;
    TFR(17) TFR(29) TFR(16) TFR(24)  x0 += ks1; x1 += ks2 + 4u;
    TFR(13) TFR(15) TFR(26) TFR(6)   x0 += ks2; x1 += ks0 + 5u;
#undef TFR
    o0 = x0; o1 = x1;
}

__device__ __forceinline__ bool better(float va, int ia, float vb, int ib) {
    return (va > vb) || (va == vb && ia < ib);
}

// ----------------- weight transpose+convert: WT[n][k] = bf16(W[k][n]) ------
__global__ __launch_bounds__(256)
void transpose_bf16(const float* __restrict__ W, unsigned short* __restrict__ WT,
                    int K, int N) {
    __shared__ float t[32][33];
    int kb = blockIdx.x * 32, nb = blockIdx.y * 32;
    int tx = threadIdx.x & 31, ty4 = threadIdx.x >> 5;
#pragma unroll
    for (int p = 0; p < 4; ++p) {
        int ky = ty4 + p * 8;
        t[ky][tx] = W[(long)(kb + ky) * N + nb + tx];
    }
    __syncthreads();
#pragma unroll
    for (int p = 0; p < 4; ++p) {
        int ny = ty4 + p * 8;
        WT[(long)(nb + ny) * K + kb + tx] = f2bf(t[tx][ny]);
    }
}

// WT3[n][0:1024]=hi, [1024:2048]=lo, [2048:3072]=hi  (for policy bf16x3)
__global__ __launch_bounds__(256)
void transpose_split3(const float* __restrict__ W, unsigned short* __restrict__ WT3,
                      int K, int N) {
    __shared__ float t[32][33];
    int kb = blockIdx.x * 32, nb = blockIdx.y * 32;
    int tx = threadIdx.x & 31, ty4 = threadIdx.x >> 5;
#pragma unroll
    for (int p = 0; p < 4; ++p) {
        int ky = ty4 + p * 8;
        t[ky][tx] = W[(long)(kb + ky) * N + nb + tx];
    }
    __syncthreads();
#pragma unroll
    for (int p = 0; p < 4; ++p) {
        int ny = ty4 + p * 8;
        float w = t[tx][ny];
        unsigned short h = f2bf(w);
        unsigned short l = f2bf(w - bf2f(h));
        long base = (long)(nb + ny) * 3072;
        WT3[base + kb + tx] = h;
        WT3[base + 1024 + kb + tx] = l;
        WT3[base + 2048 + kb + tx] = h;
    }
}

// ---------- fp32 -> bf16 hi [+ optional lo split], bit-identical RNE --------
__global__ __launch_bounds__(256)
void cvt_split(const float* __restrict__ src, unsigned short* __restrict__ hi,
               unsigned short* __restrict__ lo, long n8) {
    long i = (long)blockIdx.x * 256 + threadIdx.x;
    long stride = (long)gridDim.x * 256;
    for (; i < n8; i += stride) {
        const float* s = src + i * 8;
        float4v v0 = *(const float4v*)s;
        float4v v1 = *(const float4v*)(s + 4);
        bf16x8 h, l;
#pragma unroll
        for (int e = 0; e < 4; ++e) {
            unsigned short h0 = f2bf(v0[e]);
            h[e] = (short)h0;
            unsigned short h1 = f2bf(v1[e]);
            h[e + 4] = (short)h1;
            if (lo) {
                l[e] = (short)f2bf(v0[e] - bf2f(h0));
                l[e + 4] = (short)f2bf(v1[e] - bf2f(h1));
            }
        }
        *(bf16x8*)&hi[i * 8] = h;
        if (lo) *(bf16x8*)&lo[i * 8] = l;
    }
}

// Rv[b][n] += rmean[b,kc*128:+128] . W[kc*128:+128, n]  (k-split, 512 blocks)
__global__ __launch_bounds__(256)
void rv2_kernel(const float* __restrict__ rmean, const float* __restrict__ W,
                float* __restrict__ Rv) {
    int blk = blockIdx.x;              // 16 b x 4 nc x 8 kc = 512
    int b = blk >> 5, nc = (blk >> 3) & 3, kc = blk & 7;
    int n = (nc << 8) + threadIdx.x;
    float s = 0.f;
    int k0 = kc << 7;
    for (int k = k0; k < k0 + 128; ++k)
        s = fmaf(rmean[b * 1024 + k], W[(long)k * 1024 + n], s);
    atomicAdd(&Rv[b * 1024 + n], s);
}

// rootmean two-stage: 256-block fp64 partials, then 64-block finish
__global__ __launch_bounds__(256)
void rootmean_part(const float* __restrict__ root, double* __restrict__ part) {
    int b = blockIdx.x >> 4, sc = blockIdx.x & 15;
#pragma unroll
    for (int hp = 0; hp < 4; ++hp) {
        int h = (hp << 8) + threadIdx.x;
        const float* base = root + (size_t)b * SHC + ((size_t)sc << 16) + h;
        double s = 0.0;
        for (int ss = 0; ss < 64; ++ss) s += (double)base[(size_t)ss << 10];
        part[(((long)b << 4) + sc) * 1024 + h] = s;
    }
}
__global__ void rootmean_fin(const double* __restrict__ part, float* __restrict__ rmean,
                             unsigned short* __restrict__ rmean_bf) {
    int e = blockIdx.x * 256 + threadIdx.x;   // 16*1024
    int b = e >> 10, h = e & 1023;
    double s = 0.0;
    for (int sc = 0; sc < 16; ++sc) s += part[(((long)b << 4) + sc) * 1024 + h];
    float v = (float)(s * (1.0 / 1024.0));
    rmean[e] = v;
    rmean_bf[e] = f2bf(v);
}

// - pipelined GEMM (bf16 MFMA, B^T weights, 3-buf counted-vmcnt, 8 waves) ---
// Block tile TM x TN, K-tile BK. 512 thr = 8 waves 2x4; wave tile
// (TM/2) x (TN/4). THREE LDS buffers; per K-step: wait vmcnt(3) [stage(it)'s
// G=3 glls done; stage(it+1)'s stay in flight] -> raw s_barrier ->
// stage(it+2) -> compute(it). Each stage gets ~2 compute phases to land.
// Swizzle involution: BK=64: c^(r&7); BK=32: c^((r>>1)&3) [0-conflict].
// A dual source w/ gathers. Pre (fp32 [16][1024], row via r2s) pre-gelu.
// EPI=0: C/Cbf (+gelu,+Cadd). EPI=1: fused focus-logit epilogue.
template<int TM, int TN, int BK, int EPI>
__global__ __launch_bounds__(512)
void gemm_bt(const unsigned short* __restrict__ Av1, long lda1, const int* __restrict__ a1rows,
             const unsigned short* __restrict__ Av2, long lda2, const int* __restrict__ a2rows,
             int K1, int kmod1,
             const unsigned short* __restrict__ WT,
             const float* __restrict__ bias,
             const float* __restrict__ wp2m, double* __restrict__ fl64,
             const float* __restrict__ Pre,
             const float* __restrict__ Cadd,
             float* __restrict__ C,
             unsigned short* __restrict__ Cbf,
             long ldc, int M, int N, int K, int doGelu) {
    constexpr int MT = TM / 32;
    constexpr int NT = TN / 64;
    constexpr int WROWS = TM / 2;
    constexpr int WCOLS = TN / 4;
    constexpr int CH = BK / 8;
    constexpr int ASLOT = TM * CH;
    constexpr int BSLOT = TN * CH;
    static_assert(ASLOT % 512 == 0 && BSLOT % 512 == 0, "full-thread staging");
    static_assert(ASLOT / 512 + BSLOT / 512 == 3, "G must be 3 for vmcnt(3)");
    __shared__ unsigned short As[3][TM * BK];
    __shared__ unsigned short Bs[3][TN * BK];
    __shared__ int r1s[TM], r2s[TM];
    int tid = threadIdx.x;
    int bx, by; swz_block(bx, by);
    int row0 = by * TM, col0 = bx * TN;
    if (tid < TM) {
        int gm = row0 + tid; if (gm >= M) gm = M - 1;
        r1s[tid] = a1rows ? a1rows[gm] : gm;
        r2s[tid] = a2rows ? a2rows[gm] : gm;
    }
    int wid = tid >> 6, lane = tid & 63;
    int wr = wid >> 2, wc = wid & 3;
    int llo = lane & 15, lhi = lane >> 4;
    auto swzc = [](int cs, int r) -> int {
        if constexpr (BK == 64) return cs ^ (r & 7);
        else                    return cs ^ ((r >> 1) & 3);
    };
    f32x4 acc[MT][NT];
#pragma unroll
    for (int i = 0; i < MT; i++)
#pragma unroll
        for (int j = 0; j < NT; j++) acc[i][j] = (f32x4){0.f, 0.f, 0.f, 0.f};
    __syncthreads();                               // r1s/r2s visible

    auto stage = [&](int k0, int b) {
#pragma unroll
        for (int i = 0; i < BSLOT / 512; ++i) {
            int q = tid + (i << 9);
            int r = q / CH, cs = q % CH, c = swzc(cs, r);
            gll16(WT + (long)(col0 + r) * K + (k0 + (c << 3)),
                  (char*)Bs[b] + (q << 4));
        }
        bool s1 = (k0 < K1);
        const unsigned short* Ab = s1 ? Av1 : Av2;
        const int* rsel = s1 ? r1s : r2s;
        long lda = s1 ? lda1 : lda2;
        int kb = s1 ? (k0 & kmod1) : (k0 - K1);
#pragma unroll
        for (int i = 0; i < ASLOT / 512; ++i) {
            int q = tid + (i << 9);
            int r = q / CH, cs = q % CH, c = swzc(cs, r);
            gll16(Ab + (long)rsel[r] * lda + (kb + (c << 3)),
                  (char*)As[b] + (q << 4));
        }
    };

    int nIt = K / BK;
    stage(0, 0);
    if (nIt > 1) stage(BK, 1);
    for (int it = 0; it < nIt; ++it) {
        int cur = it % 3;
        if (it + 1 < nIt) {
            asm volatile("s_waitcnt vmcnt(3)" ::: "memory");   // stage(it) landed
        } else {
            asm volatile("s_waitcnt vmcnt(0)" ::: "memory");   // last tile
        }
        __builtin_amdgcn_s_barrier();
        __builtin_amdgcn_sched_barrier(0);
        if (it + 2 < nIt) stage((it + 2) * BK, (it + 2) % 3);
        char* AsB = (char*)As[cur];
        char* BsB = (char*)Bs[cur];
#pragma unroll
        for (int ks = 0; ks < BK / 32; ++ks) {
            bf16x8 af[MT], bfv[NT];
#pragma unroll
            for (int mt = 0; mt < MT; ++mt) {
                int r = wr * WROWS + mt * 16 + llo;
                int pc = swzc((ks << 2) | lhi, r);
                af[mt] = *(const bf16x8*)(AsB + ((r * CH + pc) << 4));
            }
#pragma unroll
            for (int nt = 0; nt < NT; ++nt) {
                int r = wc * WCOLS + nt * 16 + llo;
                int pc = swzc((ks << 2) | lhi, r);
                bfv[nt] = *(const bf16x8*)(BsB + ((r * CH + pc) << 4));
            }
#pragma unroll
            for (int mt = 0; mt < MT; ++mt)
#pragma unroll
                for (int nt = 0; nt < NT; ++nt)
                    acc[mt][nt] = __builtin_amdgcn_mfma_f32_16x16x32_bf16(
                        af[mt], bfv[nt], acc[mt][nt], 0, 0, 0);
        }
    }
    // epilogue: C/D col=lane&15, row=(lane>>4)*4+reg  [m89-verified]
    if constexpr (EPI == 0) {
#pragma unroll
        for (int mt = 0; mt < MT; ++mt) {
#pragma unroll
            for (int nt = 0; nt < NT; ++nt) {
                int gn = col0 + wc * WCOLS + nt * 16 + llo;
#pragma unroll
                for (int r = 0; r < 4; ++r) {
                    int rl = wr * WROWS + mt * 16 + lhi * 4 + r;
                    int gm = row0 + rl;
                    if (gm >= M) continue;
                    float v = acc[mt][nt][r] + bias[gn];
                    if (Pre) v += Pre[(long)r2s[rl] * 1024 + gn];
                    if (doGelu) v = gelu32(v);
                    if (Cadd) v += Cadd[(long)gm * ldc + gn];
                    if (C)   C[(long)gm * ldc + gn] = v;
                    if (Cbf) Cbf[(long)gm * ldc + gn] = f2bf(v);
                }
            }
        }
    } else {
        // fused focus-logit: fl64[m] += sum_n gelu(x)*wp2m[n]
#pragma unroll
        for (int mt = 0; mt < MT; ++mt) {
            double part[4] = {0.0, 0.0, 0.0, 0.0};
#pragma unroll
            for (int nt = 0; nt < NT; ++nt) {
                int gn = col0 + wc * WCOLS + nt * 16 + llo;
                float b = bias[gn], wn = wp2m[gn];
#pragma unroll
                for (int r = 0; r < 4; ++r) {
                    float x = acc[mt][nt][r] + b;
                    part[r] += (double)gelu32(x) * (double)wn;
                }
            }
#pragma unroll
            for (int r = 0; r < 4; ++r) {
                double v = part[r];
                v += __shfl_xor(v, 1);
                v += __shfl_xor(v, 2);
                v += __shfl_xor(v, 4);
                v += __shfl_xor(v, 8);
                if (llo == 0)
                    atomicAdd(&fl64[row0 + wr * WROWS + mt * 16 + lhi * 4 + r], v);
            }
        }
    }
}

__global__ void flbuild_kernel(const double* __restrict__ fl64,
                               const float* __restrict__ wp2m,
                               const int* __restrict__ amask,
                               float* __restrict__ fl32) {
    int m = blockIdx.x * 256 + threadIdx.x;
    fl32[m] = (amask[m] == 0) ? -1e9f : (float)(fl64[m] + (double)wp2m[1024]);
}

// --------------------------- small kernels ---------------------------------
__global__ void wp2mean_kernel(const float* __restrict__ Wp2,
                               const float* __restrict__ bp2,
                               float* __restrict__ outv) {
    __shared__ double sb[256];
    int r = blockIdx.x, tid = threadIdx.x;
    const float* src = (r < 1024) ? (Wp2 + (size_t)r * 1024) : bp2;
    double s = 0.0;
    for (int k = tid; k < 1024; k += 256) s += (double)src[k];
    sb[tid] = s; __syncthreads();
    for (int off = 128; off > 0; off >>= 1) {
        if (tid < off) sb[tid] += sb[tid + off];
        __syncthreads();
    }
    if (tid == 0) outv[r] = (float)(sb[0] * (1.0 / 1024.0));
}

__global__ __launch_bounds__(256)
void ctrl_fc1(const float* __restrict__ root, const float* __restrict__ W,
              const float* __restrict__ b1, float* __restrict__ T1) {
    __shared__ double red[16][17];
    int ni = threadIdx.x & 15, kt = threadIdx.x >> 4;
    int n = blockIdx.x * 16 + ni;
    double accb[16];
#pragma unroll
    for (int bb = 0; bb < 16; ++bb) accb[bb] = 0.0;
    for (int k = kt * 64; k < kt * 64 + 64; ++k) {
        double w = (double)W[(long)k * 1024 + n];
#pragma unroll
        for (int bb = 0; bb < 16; ++bb)
            accb[bb] = fma((double)root[(long)bb * SHC + k], w, accb[bb]);
    }
    for (int bb = 0; bb < 16; ++bb) {
        red[kt][ni] = accb[bb];
        __syncthreads();
        if (kt == 0) {
            double s = 0.0;
            for (int q = 0; q < 16; ++q) s += red[q][ni];
            double x = s + (double)b1[n];
            T1[bb * 1024 + n] = (float)(0.5 * x * (1.0 + erf(x * 0.70710678118654752440)));
        }
        __syncthreads();
    }
}

__global__ void ctrl_fc2(const float* __restrict__ T1, const float* __restrict__ W2,
                         const float* __restrict__ b2, float* __restrict__ logits) {
    __shared__ double sb[256];
    int bn = blockIdx.x;
    int b = bn / 5, n = bn % 5;
    double s = 0.0;
    for (int k = threadIdx.x; k < 1024; k += 256)
        s += (double)T1[b * 1024 + k] * (double)W2[k * 5 + n];
    sb[threadIdx.x] = s; __syncthreads();
    for (int off = 128; off > 0; off >>= 1) {
        if (threadIdx.x < off) sb[threadIdx.x] += sb[threadIdx.x + off];
        __syncthreads();
    }
    if (threadIdx.x == 0) logits[b * 5 + n] = (float)(sb[0] + (double)b2[n]);
}

__global__ void sims_kernel(const float* __restrict__ logits, int* __restrict__ sims) {
    int b = threadIdx.x;
    if (b >= BATCH) return;
    float best = logits[b * 5 + 0]; int biv = 0;
    for (int i = 1; i < 5; i++) {
        float v = logits[b * 5 + i];
        if (v > best) { best = v; biv = i; }
    }
    const int opt[5] = {10, 25, 50, 75, 100};
    sims[b] = opt[biv];
}

// Per (t,b): JAX PARTITIONABLE threefry (byte-identical to rounds 5-20)
__global__ void gumbel_kernel(const float* __restrict__ fl,
                              int* __restrict__ idxj, int* __restrict__ vidx) {
    __shared__ float sv[256][3];
    __shared__ int   si[256][3];
    int blk = blockIdx.x;           // c = t*16+b
    int t = blk >> 4, b = blk & 15;
    uint32_t kk0, kk1;
    threefry(0u, 42u, 0u, (uint32_t)t, kk0, kk1);   // fold_in(key(42), t)
    int tid = threadIdx.x;
    float bv[3] = {-INFINITY, -INFINITY, -INFINITY};
    int   bi[3] = {0x7FFFFFFF, 0x7FFFFFFF, 0x7FFFFFFF};
    for (int s = tid; s < SEQ; s += 256) {
        uint32_t m = (uint32_t)(b * SEQ + s);
        uint32_t y0, y1;
        threefry(kk0, kk1, 0u, m, y0, y1);
        uint32_t bits = y0 ^ y1;
        float f = __uint_as_float((bits >> 9) | 0x3F800000u) - 1.0f;
        float u = fmaxf(1.17549435e-38f, f);
        float l1 = (float)log((double)u);
        float l2 = (float)log(-(double)l1);
        float g  = -l2;
        float val = fl[b * SEQ + s] + g;
        if (better(val, s, bv[2], bi[2])) {
            bv[2] = val; bi[2] = s;
            if (better(bv[2], bi[2], bv[1], bi[1])) {
                float tv = bv[1]; int ti = bi[1];
                bv[1] = bv[2]; bi[1] = bi[2]; bv[2] = tv; bi[2] = ti;
            }
            if (better(bv[1], bi[1], bv[0], bi[0])) {
                float tv = bv[0]; int ti = bi[0];
                bv[0] = bv[1]; bi[0] = bi[1]; bv[1] = tv; bi[1] = ti;
            }
        }
    }
    sv[tid][0] = bv[0]; sv[tid][1] = bv[1]; sv[tid][2] = bv[2];
    si[tid][0] = bi[0]; si[tid][1] = bi[1]; si[tid][2] = bi[2];
    __syncthreads();
    for (int off = 128; off > 0; off >>= 1) {
        if (tid < off) {
            float av[3] = {sv[tid][0], sv[tid][1], sv[tid][2]};
            int   ai[3] = {si[tid][0], si[tid][1], si[tid][2]};
            float cv[3] = {sv[tid + off][0], sv[tid + off][1], sv[tid + off][2]};
            int   ci[3] = {si[tid + off][0], si[tid + off][1], si[tid + off][2]};
            float rv[3]; int ri[3]; int pa = 0, pb = 0;
#pragma unroll
            for (int r = 0; r < 3; r++) {
                if (better(av[pa], ai[pa], cv[pb], ci[pb])) { rv[r] = av[pa]; ri[r] = ai[pa]; pa++; }
                else                                        { rv[r] = cv[pb]; ri[r] = ci[pb]; pb++; }
            }
            sv[tid][0] = rv[0]; sv[tid][1] = rv[1]; sv[tid][2] = rv[2];
            si[tid][0] = ri[0]; si[tid][1] = ri[1]; si[tid][2] = ri[2];
        }
        __syncthreads();
    }
    if (tid == 0) {
        idxj[0 * NCHAIN + blk] = b * SEQ + si[0][0];
        idxj[1 * NCHAIN + blk] = b * SEQ + si[0][1];
        idxj[2 * NCHAIN + blk] = b * SEQ + si[0][2];
        vidx[blk] = b;
    }
}

// vidx3[m] = m & 15 (batch id for all 4800 batched-transition rows)
__global__ void vidx3_kernel(int* __restrict__ vidx3) {
    int m = blockIdx.x * 256 + threadIdx.x;
    if (m < NCH3) vidx3[m] = m & 15;
}

// mean_cur_bf[c][h] = bf16(rmean[b][h] + sum_j (NS[j,c,h] - root[idxj,h])/1024)
__global__ void meanfinal_kernel(const float* __restrict__ rmean,
                                 const float* __restrict__ NS,
                                 const float* __restrict__ root,
                                 const int* __restrict__ idxj,
                                 unsigned short* __restrict__ mc_bf) {
    int e = blockIdx.x * 256 + threadIdx.x;
    int c = e >> 10, hh = e & 1023;
    double m = (double)rmean[(c & 15) * HDIM + hh];
#pragma unroll
    for (int j = 0; j < 3; ++j) {
        int r = idxj[j * NCHAIN + c];
        m += ((double)NS[((long)j * NCHAIN + c) * 1024 + hh] -
              (double)root[(long)r * 1024 + hh]) * (1.0 / 1024.0);
    }
    mc_bf[e] = f2bf((float)m);
}

__global__ void valdot_kernel(const float* __restrict__ HV, const float* __restrict__ Wav2,
                              const float* __restrict__ bav2, float* __restrict__ w) {
    __shared__ double sb[256];
    int c = blockIdx.x, tid = threadIdx.x;
    double s = 0.0;
    for (int k = tid; k < HDIM; k += 256) s += (double)HV[(size_t)c * HDIM + k] * (double)Wav2[k];
    sb[tid] = s; __syncthreads();
    for (int off = 128; off > 0; off >>= 1) {
        if (tid < off) sb[tid] += sb[tid + off];
        __syncthreads();
    }
    if (tid == 0) {
        double v = sb[0] + (double)bav2[0];
        w[c] = (float)(1.0 / (1.0 + exp(-v)));
    }
}

__global__ void wsum_kernel(const float* __restrict__ w, const int* __restrict__ sims,
                            double* __restrict__ Wsum) {
    int b = threadIdx.x;
    if (b >= BATCH) return;
    int sb = sims[b];
    double s = 0.0;
    for (int t = 0; t < sb; t++) s += (double)w[t * BATCH + b];
    Wsum[b] = s;
}

// acc init (out + acc_bf in one pass)
__global__ void accinit2_kernel(const float* __restrict__ root,
                                const double* __restrict__ Wsum,
                                float* __restrict__ acc,
                                unsigned short* __restrict__ acc_bf) {
    size_t e = (size_t)blockIdx.x * 256 + threadIdx.x;
    int b = (int)(e >> 20);
    float v = (float)((1.0 + Wsum[b]) * (double)root[e]);
    acc[e] = v;
    acc_bf[e] = f2bf(v);
}

__global__ __launch_bounds__(256)
void corrections_atomic(const float* __restrict__ NS, const float* __restrict__ root,
                        const float* __restrict__ w, const int* __restrict__ sims,
                        const int* __restrict__ idxj, float* __restrict__ acc) {
    int blk = blockIdx.x;                // 0..4799
    int j = blk / NCHAIN, c = blk % NCHAIN;
    int b = c & 15, t = c >> 4;
    if (t >= sims[b]) return;
    float wv = w[c];
    int row = idxj[j * NCHAIN + c];
    const float* ns = NS + ((long)j * NCHAIN + c) * 1024;
    const float* rt = root + (long)row * 1024;
    float* ac = acc + (long)row * 1024;
    for (int h = threadIdx.x; h < 1024; h += 256)
        atomicAdd(&ac[h], wv * (ns[h] - rt[h]));
}

// reconvert touched rows (idempotent across duplicates)
__global__ __launch_bounds__(256)
void reconv_kernel(const float* __restrict__ acc, const int* __restrict__ idxj,
                   unsigned short* __restrict__ acc_bf) {
    int row = idxj[blockIdx.x];          // 0..4799 entries
    const float* src = acc + (long)row * 1024;
    unsigned short* dst = acc_bf + (long)row * 1024;
    for (int h = threadIdx.x; h < 1024; h += 256)
        dst[h] = f2bf(src[h]);
}

// ------------------------------- launch ------------------------------------
extern "C" void kernel_launch(void* const* d_in, const int* in_sizes, int n_in,
                              void* d_out, int out_size, void* d_ws, size_t ws_size,
                              hipStream_t stream) {
    (void)in_sizes; (void)n_in; (void)out_size; (void)ws_size;
    const float* root = (const float*)d_in[0];
    const int*   amask = (const int*)d_in[1];
    const float* Wsc1 = (const float*)d_in[2];  const float* bsc1 = (const float*)d_in[3];
    const float* Wsc2 = (const float*)d_in[4];  const float* bsc2 = (const float*)d_in[5];
    const float* Wp1  = (const float*)d_in[6];  const float* bp1  = (const float*)d_in[7];
    const float* Wp2  = (const float*)d_in[8];  const float* bp2  = (const float*)d_in[9];
    const float* Wt1  = (const float*)d_in[10]; const float* bt1  = (const float*)d_in[11];
    const float* Wt2  = (const float*)d_in[12]; const float* bt2  = (const float*)d_in[13];
    const float* Wav1 = (const float*)d_in[14]; const float* bav1 = (const float*)d_in[15];
    const float* Wav2 = (const float*)d_in[16]; const float* bav2 = (const float*)d_in[17];
    const float* Wg1  = (const float*)d_in[18]; const float* bg1  = (const float*)d_in[19];
    const float* Wg2  = (const float*)d_in[20]; const float* bg2  = (const float*)d_in[21];
    float* out = (float*)d_out;

    // ---- workspace carving (~118 MB) ----
    char* p = (char*)d_ws;
    auto carve = [&](size_t nbytes) -> void* {
        void* r = (void*)p; p += (nbytes + 255) & ~(size_t)255; return r;
    };
    unsigned short* H1big = (unsigned short*)carve((size_t)NCH3 * HDIM * 2);
    float*          Hav   = (float*)carve((size_t)NCHAIN * HDIM * 4);
    float*          NS    = (float*)carve((size_t)3 * NCHAIN * HDIM * 4);
    unsigned short* h_bf  = (unsigned short*)H1big;  // step-9 alias (tenants dead)
    unsigned short* WT3   = (unsigned short*)NS;     // dead before NS written
    unsigned short* WTt1  = (unsigned short*)carve((size_t)1024 * 1024 * 2);  // Wt1[1024:2048]
    unsigned short* WTt2  = (unsigned short*)carve((size_t)1024 * 1024 * 2);
    unsigned short* WTav1 = (unsigned short*)carve((size_t)1024 * 1024 * 2);  // Wav1[1024:2048]
    unsigned short* WTg1  = (unsigned short*)carve((size_t)1024 * 2048 * 2);
    unsigned short* WTg2  = (unsigned short*)carve((size_t)1024 * 1024 * 2);
    float*  rmean  = (float*)carve(BATCH * HDIM * 4);
    float*  Rv_t   = (float*)carve(BATCH * HDIM * 4);
    float*  Rv_av  = (float*)carve(BATCH * HDIM * 4);
    double* rpart  = (double*)carve((size_t)BATCH * 16 * HDIM * 8);
    float*  T1     = (float*)carve(BATCH * HDIM * 4);
    float*  logits = (float*)carve(128 * 4);
    float*  wp2m   = (float*)carve(1040 * 4);
    double* fl64   = (double*)carve((size_t)BATCH * SEQ * 8);
    float*  fl32   = (float*)carve(BATCH * SEQ * 4);
    float*  wbuf   = (float*)carve(NCHAIN * 4);
    double* Wsumd  = (double*)carve(64 * 8);
    int*    sims   = (int*)carve(64 * 4);
    int*    idxj   = (int*)carve(3 * NCHAIN * 4);
    int*    vidx   = (int*)carve(NCHAIN * 4);
    int*    vidx3  = (int*)carve(NCH3 * 4);
    unsigned short* root_bf     = (unsigned short*)carve((size_t)BATCH * SEQ * HDIM * 2);
    unsigned short* acc_bf      = (unsigned short*)carve((size_t)BATCH * SEQ * HDIM * 2);
    unsigned short* root_lo     = acc_bf;   // policy (step 4) dead before acc_bf (step 8)
    unsigned short* mean_cur_bf = (unsigned short*)carve((size_t)NCHAIN * HDIM * 2);
    unsigned short* rmean_bf    = (unsigned short*)carve(BATCH * HDIM * 2);

    const long NTOT8 = (long)BATCH * SEQ * HDIM / 8;
    const int  KBIG = 1 << 30, KMA = 0x7FFFFFFF;

    // 1) weight transposes (+ policy hi/lo triple-stack)
    transpose_bf16<<<dim3(1024 / 32, 1024 / 32), 256, 0, stream>>>(
        Wt1 + (size_t)1024 * 1024, WTt1, 1024, 1024);
    transpose_bf16<<<dim3(1024 / 32, 1024 / 32), 256, 0, stream>>>(Wt2, WTt2, 1024, 1024);
    transpose_bf16<<<dim3(1024 / 32, 1024 / 32), 256, 0, stream>>>(
        Wav1 + (size_t)1024 * 1024, WTav1, 1024, 1024);
    transpose_bf16<<<dim3(2048 / 32, 1024 / 32), 256, 0, stream>>>(Wg1, WTg1, 2048, 1024);
    transpose_bf16<<<dim3(1024 / 32, 1024 / 32), 256, 0, stream>>>(Wg2, WTg2, 1024, 1024);
    transpose_split3<<<dim3(32, 32), 256, 0, stream>>>(Wp1, WT3, 1024, 1024);
    // 1b) root -> bf16 hi+lo once (root_lo aliases acc_bf); vidx3 init
    cvt_split<<<2048, 256, 0, stream>>>(root, root_bf, root_lo, NTOT8);
    vidx3_kernel<<<(NCH3 + 255) / 256, 256, 0, stream>>>(vidx3);
    hipMemsetAsync(Rv_t, 0, BATCH * HDIM * 4, stream);
    hipMemsetAsync(Rv_av, 0, BATCH * HDIM * 4, stream);
    // 2) wp2 means, root mean (two-stage), Rv's
    wp2mean_kernel<<<1025, 256, 0, stream>>>(Wp2, bp2, wp2m);
    rootmean_part<<<256, 256, 0, stream>>>(root, rpart);
    rootmean_fin<<<64, 256, 0, stream>>>(rpart, rmean, rmean_bf);
    rv2_kernel<<<512, 256, 0, stream>>>(rmean, Wt1, Rv_t);     // Wt1 top half
    rv2_kernel<<<512, 256, 0, stream>>>(rmean, Wav1, Rv_av);   // Wav1 top half
    // 3) controller (fp64) -> sims
    ctrl_fc1<<<64, 256, 0, stream>>>(root, Wsc1, bsc1, T1);
    ctrl_fc2<<<80, 256, 0, stream>>>(T1, Wsc2, bsc2, logits);
    sims_kernel<<<1, 64, 0, stream>>>(logits, sims);
    // 4) policy as pipelined K=3072 GEMM ([hi|hi|lo]), 128x256, BK=32
    hipMemsetAsync(fl64, 0, (size_t)BATCH * SEQ * 8, stream);
    gemm_bt<128, 256, 32, 1><<<dim3(4, 128), 512, 0, stream>>>(
        root_bf, 1024, nullptr, root_lo, 1024, nullptr, 2048, 1023,
        WT3, bp1, wp2m, fl64, nullptr, nullptr, nullptr, nullptr, 1024,
        BATCH * SEQ, 1024, 3072, 0);
    flbuild_kernel<<<BATCH * SEQ / 256, 256, 0, stream>>>(fl64, wp2m, amask, fl32);
    // 5) gumbel top-3 (partitionable threefry, unchanged)
    gumbel_kernel<<<NCHAIN, 256, 0, stream>>>(fl32, idxj, vidx);
    // 6) transitions BATCHED over 4800 rows, K=1024 (mean half via Rv_t/Pre)
    gemm_bt<64, 128, 64, 0><<<dim3(8, 75), 512, 0, stream>>>(
        root_bf, 1024, idxj, nullptr, 0, vidx3, KBIG, KMA,
        WTt1, bt1, nullptr, nullptr, Rv_t, nullptr, nullptr, H1big, 1024,
        NCH3, 1024, 1024, 1);
    gemm_bt<64, 128, 64, 0><<<dim3(8, 75), 512, 0, stream>>>(
        H1big, 1024, nullptr, nullptr, 0, nullptr, KBIG, KMA,
        WTt2, bt2, nullptr, nullptr, nullptr, nullptr, NS, nullptr,
        1024, NCH3, 1024, 1024, 0);
    // 6b) exact final per-chain mean for the value path
    meanfinal_kernel<<<NCHAIN * HDIM / 256, 256, 0, stream>>>(
        rmean, NS, root, idxj, mean_cur_bf);
    // 7) action value: K=1024 on mean_cur (rmean half via Rv_av/Pre) -> w
    gemm_bt<64, 128, 64, 0><<<dim3(8, 25), 512, 0, stream>>>(
        mean_cur_bf, 1024, nullptr, nullptr, 0, vidx, KBIG, KMA,
        WTav1, bav1, nullptr, nullptr, Rv_av, nullptr, Hav, nullptr, 1024,
        NCHAIN, 1024, 1024, 1);
    valdot_kernel<<<NCHAIN, 256, 0, stream>>>(Hav, Wav2, bav2, wbuf);
    wsum_kernel<<<1, 64, 0, stream>>>(wbuf, sims, Wsumd);
    // 8) acc (in d_out): init(+bf16) + parallel corrections + touched-row reconv
    accinit2_kernel<<<(BATCH * SEQ * HDIM) / 256, 256, 0, stream>>>(
        root, Wsumd, out, acc_bf);
    corrections_atomic<<<3 * NCHAIN, 256, 0, stream>>>(NS, root, wbuf, sims, idxj, out);
    reconv_kernel<<<NCH3, 256, 0, stream>>>(out, idxj, acc_bf);
    // 9) aggregation (128x256, BK=32, pipelined)
    gemm_bt<128, 256, 32, 0><<<dim3(4, 128), 512, 0, stream>>>(
        root_bf, 1024, nullptr, acc_bf, 1024, nullptr, 1024, KMA,
        WTg1, bg1, nullptr, nullptr, nullptr, nullptr, nullptr, h_bf, 1024,
        BATCH * SEQ, 1024, 2048, 1);
    gemm_bt<128, 256, 32, 0><<<dim3(4, 128), 512, 0, stream>>>(
        h_bf, 1024, nullptr, nullptr, 0, nullptr, KBIG, KMA,
        WTg2, bg2, nullptr, nullptr, nullptr, root, out, nullptr, 1024,
        BATCH * SEQ, 1024, 1024, 0);
}

// Round 22
// 593.770 us; speedup vs baseline: 1.0762x; 1.0762x over previous
//
#include <hip/hip_runtime.h>
#include <hip/hip_bf16.h>
#include <cstdint>
#include <math.h>

// ---------------------------------------------------------------------------
// AdaptiveMCTSReasoner  B=16, S=1024, H=1024, MAX_SIMS=100, K_FOCUS=3
// Round 22: recombination of best-measured configs.
//  - gemm_bt: REVERT to R20's 2-buffer __syncthreads loop (R21's counted
//    vmcnt 3-buf regressed: T4 needs 8-phase interleave per guide m218/m230;
//    grafted on a 1-phase loop it cost ~4%).
//  - KEEP R21's accinit2 (+acc_bf) + touched-row reconv (drops the full
//    96MB cvt pass; bit-identical numerics).
// Selection path byte-identical to rounds 5-21 (passing, absmax 0.5).
// ---------------------------------------------------------------------------

#define SEQ 1024
#define BATCH 16
#define HDIM 1024
#define NSIM 100
#define NCHAIN (NSIM * BATCH)   // 1600
#define NCH3 (3 * NCHAIN)       // 4800
#define SHC (SEQ * HDIM)

typedef short bf16x8 __attribute__((ext_vector_type(8)));
typedef float f32x4 __attribute__((ext_vector_type(4)));
typedef float float4v __attribute__((ext_vector_type(4)));

__device__ __forceinline__ unsigned short f2bf(float f) {
    union { float f; uint32_t u; } c; c.f = f;
    uint32_t u = c.u;
    return (unsigned short)((u + 0x7FFFu + ((u >> 16) & 1u)) >> 16);   // RNE
}
__device__ __forceinline__ float bf2f(unsigned short h) {
    union { uint32_t u; float f; } c; c.u = ((uint32_t)h) << 16;
    return c.f;
}

__device__ __forceinline__ void gll16(const void* g, void* l) {
    __builtin_amdgcn_global_load_lds(
        (const __attribute__((address_space(1))) void*)g,
        (__attribute__((address_space(3))) void*)l, 16, 0, 0);
}

__device__ __forceinline__ float gelu32(float x) {
    return 0.5f * x * (1.0f + erff(x * 0.70710678f));
}

// XCD-aware bijective swizzle (requires nwg % 8 == 0; all our grids qualify)
__device__ __forceinline__ void swz_block(int& bx, int& by) {
    int gx = gridDim.x;
    int h = blockIdx.y * gx + blockIdx.x;
    int nwg = gx * gridDim.y;
    int l = (h & 7) * (nwg >> 3) + (h >> 3);
    bx = l % gx; by = l / gx;
}

// ------------------------------- threefry ----------------------------------
__device__ __forceinline__ uint32_t rotl32(uint32_t v, int r) {
    return (v << r) | (v >> (32 - r));
}

__device__ __forceinline__ void threefry(uint32_t k0, uint32_t k1,
                                         uint32_t c0, uint32_t c1,
                                         uint32_t& o0, uint32_t& o1) {
    uint32_t ks0 = k0, ks1 = k1, ks2 = k0 ^ k1 ^ 0x1BD11BDAu;
    uint32_t x0 = c0 + ks0, x1 = c1 + ks1;
#define TFR(r) { x0 += x1; x1 = rotl32(x1, r); x1 ^= x0; }
    TFR(13) TFR(15) TFR(26) TFR(6)   x0 += ks1; x1 += ks2 + 1u;
    TFR(17) TFR(29) TFR(16) TFR(24)  x0 += ks2; x1 += ks0 + 2u;
    TFR(13) TFR(15) TFR(26) TFR(6)   x0 += ks0; x1 += ks1 + 3u;
    TFR(17) TFR(29) TFR(16) TFR(24)  x0 += ks1; x1 += ks2 + 4u;
    TFR(13) TFR(15) TFR(26) TFR(6)   x0 += ks2; x1 += ks0 + 5u;
#undef TFR
    o0 = x0; o1 = x1;
}

__device__ __forceinline__ bool better(float va, int ia, float vb, int ib) {
    return (va > vb) || (va == vb && ia < ib);
}

// ----------------- weight transpose+convert: WT[n][k] = bf16(W[k][n]) ------
__global__ __launch_bounds__(256)
void transpose_bf16(const float* __restrict__ W, unsigned short* __restrict__ WT,
                    int K, int N) {
    __shared__ float t[32][33];
    int kb = blockIdx.x * 32, nb = blockIdx.y * 32;
    int tx = threadIdx.x & 31, ty4 = threadIdx.x >> 5;
#pragma unroll
    for (int p = 0; p < 4; ++p) {
        int ky = ty4 + p * 8;
        t[ky][tx] = W[(long)(kb + ky) * N + nb + tx];
    }
    __syncthreads();
#pragma unroll
    for (int p = 0; p < 4; ++p) {
        int ny = ty4 + p * 8;
        WT[(long)(nb + ny) * K + kb + tx] = f2bf(t[tx][ny]);
    }
}

// WT3[n][0:1024]=hi, [1024:2048]=lo, [2048:3072]=hi  (for policy bf16x3)
__global__ __launch_bounds__(256)
void transpose_split3(const float* __restrict__ W, unsigned short* __restrict__ WT3,
                      int K, int N) {
    __shared__ float t[32][33];
    int kb = blockIdx.x * 32, nb = blockIdx.y * 32;
    int tx = threadIdx.x & 31, ty4 = threadIdx.x >> 5;
#pragma unroll
    for (int p = 0; p < 4; ++p) {
        int ky = ty4 + p * 8;
        t[ky][tx] = W[(long)(kb + ky) * N + nb + tx];
    }
    __syncthreads();
#pragma unroll
    for (int p = 0; p < 4; ++p) {
        int ny = ty4 + p * 8;
        float w = t[tx][ny];
        unsigned short h = f2bf(w);
        unsigned short l = f2bf(w - bf2f(h));
        long base = (long)(nb + ny) * 3072;
        WT3[base + kb + tx] = h;
        WT3[base + 1024 + kb + tx] = l;
        WT3[base + 2048 + kb + tx] = h;
    }
}

// ---------- fp32 -> bf16 hi [+ optional lo split], bit-identical RNE --------
__global__ __launch_bounds__(256)
void cvt_split(const float* __restrict__ src, unsigned short* __restrict__ hi,
               unsigned short* __restrict__ lo, long n8) {
    long i = (long)blockIdx.x * 256 + threadIdx.x;
    long stride = (long)gridDim.x * 256;
    for (; i < n8; i += stride) {
        const float* s = src + i * 8;
        float4v v0 = *(const float4v*)s;
        float4v v1 = *(const float4v*)(s + 4);
        bf16x8 h, l;
#pragma unroll
        for (int e = 0; e < 4; ++e) {
            unsigned short h0 = f2bf(v0[e]);
            h[e] = (short)h0;
            unsigned short h1 = f2bf(v1[e]);
            h[e + 4] = (short)h1;
            if (lo) {
                l[e] = (short)f2bf(v0[e] - bf2f(h0));
                l[e + 4] = (short)f2bf(v1[e] - bf2f(h1));
            }
        }
        *(bf16x8*)&hi[i * 8] = h;
        if (lo) *(bf16x8*)&lo[i * 8] = l;
    }
}

// Rv[b][n] += rmean[b,kc*128:+128] . W[kc*128:+128, n]  (k-split, 512 blocks)
__global__ __launch_bounds__(256)
void rv2_kernel(const float* __restrict__ rmean, const float* __restrict__ W,
                float* __restrict__ Rv) {
    int blk = blockIdx.x;              // 16 b x 4 nc x 8 kc = 512
    int b = blk >> 5, nc = (blk >> 3) & 3, kc = blk & 7;
    int n = (nc << 8) + threadIdx.x;
    float s = 0.f;
    int k0 = kc << 7;
    for (int k = k0; k < k0 + 128; ++k)
        s = fmaf(rmean[b * 1024 + k], W[(long)k * 1024 + n], s);
    atomicAdd(&Rv[b * 1024 + n], s);
}

// rootmean two-stage: 256-block fp64 partials, then 64-block finish
__global__ __launch_bounds__(256)
void rootmean_part(const float* __restrict__ root, double* __restrict__ part) {
    int b = blockIdx.x >> 4, sc = blockIdx.x & 15;
#pragma unroll
    for (int hp = 0; hp < 4; ++hp) {
        int h = (hp << 8) + threadIdx.x;
        const float* base = root + (size_t)b * SHC + ((size_t)sc << 16) + h;
        double s = 0.0;
        for (int ss = 0; ss < 64; ++ss) s += (double)base[(size_t)ss << 10];
        part[(((long)b << 4) + sc) * 1024 + h] = s;
    }
}
__global__ void rootmean_fin(const double* __restrict__ part, float* __restrict__ rmean,
                             unsigned short* __restrict__ rmean_bf) {
    int e = blockIdx.x * 256 + threadIdx.x;   // 16*1024
    int b = e >> 10, h = e & 1023;
    double s = 0.0;
    for (int sc = 0; sc < 16; ++sc) s += part[(((long)b << 4) + sc) * 1024 + h];
    float v = (float)(s * (1.0 / 1024.0));
    rmean[e] = v;
    rmean_bf[e] = f2bf(v);
}

// - pipelined GEMM (bf16 MFMA, B^T weights, dbuf, 8 waves, swizzled LDS) ----
// Block tile TM x TN, K-tile BK. 512 thr = 8 waves 2x4; wave tile
// (TM/2) x (TN/4). Dbuf, ONE barrier per K-step (R20-proven). Swizzle
// involution: BK=64: c^(r&7); BK=32: c^((r>>1)&3) [both 0-conflict]. A dual
// source w/ gathers. Pre (fp32 [16][1024], row via r2s) added pre-gelu.
// EPI=0: C/Cbf (+gelu,+Cadd). EPI=1: fused focus-logit epilogue.
template<int TM, int TN, int BK, int EPI>
__global__ __launch_bounds__(512)
void gemm_bt(const unsigned short* __restrict__ Av1, long lda1, const int* __restrict__ a1rows,
             const unsigned short* __restrict__ Av2, long lda2, const int* __restrict__ a2rows,
             int K1, int kmod1,
             const unsigned short* __restrict__ WT,
             const float* __restrict__ bias,
             const float* __restrict__ wp2m, double* __restrict__ fl64,
             const float* __restrict__ Pre,
             const float* __restrict__ Cadd,
             float* __restrict__ C,
             unsigned short* __restrict__ Cbf,
             long ldc, int M, int N, int K, int doGelu) {
    constexpr int MT = TM / 32;
    constexpr int NT = TN / 64;
    constexpr int WROWS = TM / 2;
    constexpr int WCOLS = TN / 4;
    constexpr int CH = BK / 8;
    constexpr int ASLOT = TM * CH;
    constexpr int BSLOT = TN * CH;
    __shared__ unsigned short As[2][TM * BK];
    __shared__ unsigned short Bs[2][TN * BK];
    __shared__ int r1s[TM], r2s[TM];
    int tid = threadIdx.x;
    int bx, by; swz_block(bx, by);
    int row0 = by * TM, col0 = bx * TN;
    if (tid < TM) {
        int gm = row0 + tid; if (gm >= M) gm = M - 1;
        r1s[tid] = a1rows ? a1rows[gm] : gm;
        r2s[tid] = a2rows ? a2rows[gm] : gm;
    }
    int wid = tid >> 6, lane = tid & 63;
    int wr = wid >> 2, wc = wid & 3;
    int llo = lane & 15, lhi = lane >> 4;
    auto swzc = [](int cs, int r) -> int {
        if constexpr (BK == 64) return cs ^ (r & 7);
        else                    return cs ^ ((r >> 1) & 3);
    };
    f32x4 acc[MT][NT];
#pragma unroll
    for (int i = 0; i < MT; i++)
#pragma unroll
        for (int j = 0; j < NT; j++) acc[i][j] = (f32x4){0.f, 0.f, 0.f, 0.f};
    __syncthreads();                               // r1s/r2s visible

    auto stage = [&](int k0, int b) {
#pragma unroll
        for (int i = 0; i < (BSLOT + 511) / 512; ++i) {
            int q = tid + (i << 9);
            if (BSLOT % 512 == 0 || q < BSLOT) {
                int r = q / CH, cs = q % CH, c = swzc(cs, r);
                gll16(WT + (long)(col0 + r) * K + (k0 + (c << 3)),
                      (char*)Bs[b] + (q << 4));
            }
        }
        bool s1 = (k0 < K1);
        const unsigned short* Ab = s1 ? Av1 : Av2;
        const int* rsel = s1 ? r1s : r2s;
        long lda = s1 ? lda1 : lda2;
        int kb = s1 ? (k0 & kmod1) : (k0 - K1);
#pragma unroll
        for (int i = 0; i < (ASLOT + 511) / 512; ++i) {
            int q = tid + (i << 9);
            if (ASLOT % 512 == 0 || q < ASLOT) {
                int r = q / CH, cs = q % CH, c = swzc(cs, r);
                gll16(Ab + (long)rsel[r] * lda + (kb + (c << 3)),
                      (char*)As[b] + (q << 4));
            }
        }
    };

    stage(0, 0);
    int nIt = K / BK;
    for (int it = 0; it < nIt; ++it) {
        int cur = it & 1;
        __syncthreads();
        if (it + 1 < nIt) stage((it + 1) * BK, cur ^ 1);
        __builtin_amdgcn_sched_barrier(0);
        char* AsB = (char*)As[cur];
        char* BsB = (char*)Bs[cur];
#pragma unroll
        for (int ks = 0; ks < BK / 32; ++ks) {
            bf16x8 af[MT], bfv[NT];
#pragma unroll
            for (int mt = 0; mt < MT; ++mt) {
                int r = wr * WROWS + mt * 16 + llo;
                int pc = swzc((ks << 2) | lhi, r);
                af[mt] = *(const bf16x8*)(AsB + ((r * CH + pc) << 4));
            }
#pragma unroll
            for (int nt = 0; nt < NT; ++nt) {
                int r = wc * WCOLS + nt * 16 + llo;
                int pc = swzc((ks << 2) | lhi, r);
                bfv[nt] = *(const bf16x8*)(BsB + ((r * CH + pc) << 4));
            }
#pragma unroll
            for (int mt = 0; mt < MT; ++mt)
#pragma unroll
                for (int nt = 0; nt < NT; ++nt)
                    acc[mt][nt] = __builtin_amdgcn_mfma_f32_16x16x32_bf16(
                        af[mt], bfv[nt], acc[mt][nt], 0, 0, 0);
        }
    }
    // epilogue: C/D col=lane&15, row=(lane>>4)*4+reg  [m89-verified]
    if constexpr (EPI == 0) {
#pragma unroll
        for (int mt = 0; mt < MT; ++mt) {
#pragma unroll
            for (int nt = 0; nt < NT; ++nt) {
                int gn = col0 + wc * WCOLS + nt * 16 + llo;
#pragma unroll
                for (int r = 0; r < 4; ++r) {
                    int rl = wr * WROWS + mt * 16 + lhi * 4 + r;
                    int gm = row0 + rl;
                    if (gm >= M) continue;
                    float v = acc[mt][nt][r] + bias[gn];
                    if (Pre) v += Pre[(long)r2s[rl] * 1024 + gn];
                    if (doGelu) v = gelu32(v);
                    if (Cadd) v += Cadd[(long)gm * ldc + gn];
                    if (C)   C[(long)gm * ldc + gn] = v;
                    if (Cbf) Cbf[(long)gm * ldc + gn] = f2bf(v);
                }
            }
        }
    } else {
        // fused focus-logit: fl64[m] += sum_n gelu(x)*wp2m[n]
#pragma unroll
        for (int mt = 0; mt < MT; ++mt) {
            double part[4] = {0.0, 0.0, 0.0, 0.0};
#pragma unroll
            for (int nt = 0; nt < NT; ++nt) {
                int gn = col0 + wc * WCOLS + nt * 16 + llo;
                float b = bias[gn], wn = wp2m[gn];
#pragma unroll
                for (int r = 0; r < 4; ++r) {
                    float x = acc[mt][nt][r] + b;
                    part[r] += (double)gelu32(x) * (double)wn;
                }
            }
#pragma unroll
            for (int r = 0; r < 4; ++r) {
                double v = part[r];
                v += __shfl_xor(v, 1);
                v += __shfl_xor(v, 2);
                v += __shfl_xor(v, 4);
                v += __shfl_xor(v, 8);
                if (llo == 0)
                    atomicAdd(&fl64[row0 + wr * WROWS + mt * 16 + lhi * 4 + r], v);
            }
        }
    }
}

__global__ void flbuild_kernel(const double* __restrict__ fl64,
                               const float* __restrict__ wp2m,
                               const int* __restrict__ amask,
                               float* __restrict__ fl32) {
    int m = blockIdx.x * 256 + threadIdx.x;
    fl32[m] = (amask[m] == 0) ? -1e9f : (float)(fl64[m] + (double)wp2m[1024]);
}

// --------------------------- small kernels ---------------------------------
__global__ void wp2mean_kernel(const float* __restrict__ Wp2,
                               const float* __restrict__ bp2,
                               float* __restrict__ outv) {
    __shared__ double sb[256];
    int r = blockIdx.x, tid = threadIdx.x;
    const float* src = (r < 1024) ? (Wp2 + (size_t)r * 1024) : bp2;
    double s = 0.0;
    for (int k = tid; k < 1024; k += 256) s += (double)src[k];
    sb[tid] = s; __syncthreads();
    for (int off = 128; off > 0; off >>= 1) {
        if (tid < off) sb[tid] += sb[tid + off];
        __syncthreads();
    }
    if (tid == 0) outv[r] = (float)(sb[0] * (1.0 / 1024.0));
}

__global__ __launch_bounds__(256)
void ctrl_fc1(const float* __restrict__ root, const float* __restrict__ W,
              const float* __restrict__ b1, float* __restrict__ T1) {
    __shared__ double red[16][17];
    int ni = threadIdx.x & 15, kt = threadIdx.x >> 4;
    int n = blockIdx.x * 16 + ni;
    double accb[16];
#pragma unroll
    for (int bb = 0; bb < 16; ++bb) accb[bb] = 0.0;
    for (int k = kt * 64; k < kt * 64 + 64; ++k) {
        double w = (double)W[(long)k * 1024 + n];
#pragma unroll
        for (int bb = 0; bb < 16; ++bb)
            accb[bb] = fma((double)root[(long)bb * SHC + k], w, accb[bb]);
    }
    for (int bb = 0; bb < 16; ++bb) {
        red[kt][ni] = accb[bb];
        __syncthreads();
        if (kt == 0) {
            double s = 0.0;
            for (int q = 0; q < 16; ++q) s += red[q][ni];
            double x = s + (double)b1[n];
            T1[bb * 1024 + n] = (float)(0.5 * x * (1.0 + erf(x * 0.70710678118654752440)));
        }
        __syncthreads();
    }
}

__global__ void ctrl_fc2(const float* __restrict__ T1, const float* __restrict__ W2,
                         const float* __restrict__ b2, float* __restrict__ logits) {
    __shared__ double sb[256];
    int bn = blockIdx.x;
    int b = bn / 5, n = bn % 5;
    double s = 0.0;
    for (int k = threadIdx.x; k < 1024; k += 256)
        s += (double)T1[b * 1024 + k] * (double)W2[k * 5 + n];
    sb[threadIdx.x] = s; __syncthreads();
    for (int off = 128; off > 0; off >>= 1) {
        if (threadIdx.x < off) sb[threadIdx.x] += sb[threadIdx.x + off];
        __syncthreads();
    }
    if (threadIdx.x == 0) logits[b * 5 + n] = (float)(sb[0] + (double)b2[n]);
}

__global__ void sims_kernel(const float* __restrict__ logits, int* __restrict__ sims) {
    int b = threadIdx.x;
    if (b >= BATCH) return;
    float best = logits[b * 5 + 0]; int biv = 0;
    for (int i = 1; i < 5; i++) {
        float v = logits[b * 5 + i];
        if (v > best) { best = v; biv = i; }
    }
    const int opt[5] = {10, 25, 50, 75, 100};
    sims[b] = opt[biv];
}

// Per (t,b): JAX PARTITIONABLE threefry (byte-identical to rounds 5-21)
__global__ void gumbel_kernel(const float* __restrict__ fl,
                              int* __restrict__ idxj, int* __restrict__ vidx) {
    __shared__ float sv[256][3];
    __shared__ int   si[256][3];
    int blk = blockIdx.x;           // c = t*16+b
    int t = blk >> 4, b = blk & 15;
    uint32_t kk0, kk1;
    threefry(0u, 42u, 0u, (uint32_t)t, kk0, kk1);   // fold_in(key(42), t)
    int tid = threadIdx.x;
    float bv[3] = {-INFINITY, -INFINITY, -INFINITY};
    int   bi[3] = {0x7FFFFFFF, 0x7FFFFFFF, 0x7FFFFFFF};
    for (int s = tid; s < SEQ; s += 256) {
        uint32_t m = (uint32_t)(b * SEQ + s);
        uint32_t y0, y1;
        threefry(kk0, kk1, 0u, m, y0, y1);
        uint32_t bits = y0 ^ y1;
        float f = __uint_as_float((bits >> 9) | 0x3F800000u) - 1.0f;
        float u = fmaxf(1.17549435e-38f, f);
        float l1 = (float)log((double)u);
        float l2 = (float)log(-(double)l1);
        float g  = -l2;
        float val = fl[b * SEQ + s] + g;
        if (better(val, s, bv[2], bi[2])) {
            bv[2] = val; bi[2] = s;
            if (better(bv[2], bi[2], bv[1], bi[1])) {
                float tv = bv[1]; int ti = bi[1];
                bv[1] = bv[2]; bi[1] = bi[2]; bv[2] = tv; bi[2] = ti;
            }
            if (better(bv[1], bi[1], bv[0], bi[0])) {
                float tv = bv[0]; int ti = bi[0];
                bv[0] = bv[1]; bi[0] = bi[1]; bv[1] = tv; bi[1] = ti;
            }
        }
    }
    sv[tid][0] = bv[0]; sv[tid][1] = bv[1]; sv[tid][2] = bv[2];
    si[tid][0] = bi[0]; si[tid][1] = bi[1]; si[tid][2] = bi[2];
    __syncthreads();
    for (int off = 128; off > 0; off >>= 1) {
        if (tid < off) {
            float av[3] = {sv[tid][0], sv[tid][1], sv[tid][2]};
            int   ai[3] = {si[tid][0], si[tid][1], si[tid][2]};
            float cv[3] = {sv[tid + off][0], sv[tid + off][1], sv[tid + off][2]};
            int   ci[3] = {si[tid + off][0], si[tid + off][1], si[tid + off][2]};
            float rv[3]; int ri[3]; int pa = 0, pb = 0;
#pragma unroll
            for (int r = 0; r < 3; r++) {
                if (better(av[pa], ai[pa], cv[pb], ci[pb])) { rv[r] = av[pa]; ri[r] = ai[pa]; pa++; }
                else                                        { rv[r] = cv[pb]; ri[r] = ci[pb]; pb++; }
            }
            sv[tid][0] = rv[0]; sv[tid][1] = rv[1]; sv[tid][2] = rv[2];
            si[tid][0] = ri[0]; si[tid][1] = ri[1]; si[tid][2] = ri[2];
        }
        __syncthreads();
    }
    if (tid == 0) {
        idxj[0 * NCHAIN + blk] = b * SEQ + si[0][0];
        idxj[1 * NCHAIN + blk] = b * SEQ + si[0][1];
        idxj[2 * NCHAIN + blk] = b * SEQ + si[0][2];
        vidx[blk] = b;
    }
}

// vidx3[m] = m & 15 (batch id for all 4800 batched-transition rows)
__global__ void vidx3_kernel(int* __restrict__ vidx3) {
    int m = blockIdx.x * 256 + threadIdx.x;
    if (m < NCH3) vidx3[m] = m & 15;
}

// mean_cur_bf[c][h] = bf16(rmean[b][h] + sum_j (NS[j,c,h] - root[idxj,h])/1024)
__global__ void meanfinal_kernel(const float* __restrict__ rmean,
                                 const float* __restrict__ NS,
                                 const float* __restrict__ root,
                                 const int* __restrict__ idxj,
                                 unsigned short* __restrict__ mc_bf) {
    int e = blockIdx.x * 256 + threadIdx.x;
    int c = e >> 10, hh = e & 1023;
    double m = (double)rmean[(c & 15) * HDIM + hh];
#pragma unroll
    for (int j = 0; j < 3; ++j) {
        int r = idxj[j * NCHAIN + c];
        m += ((double)NS[((long)j * NCHAIN + c) * 1024 + hh] -
              (double)root[(long)r * 1024 + hh]) * (1.0 / 1024.0);
    }
    mc_bf[e] = f2bf((float)m);
}

__global__ void valdot_kernel(const float* __restrict__ HV, const float* __restrict__ Wav2,
                              const float* __restrict__ bav2, float* __restrict__ w) {
    __shared__ double sb[256];
    int c = blockIdx.x, tid = threadIdx.x;
    double s = 0.0;
    for (int k = tid; k < HDIM; k += 256) s += (double)HV[(size_t)c * HDIM + k] * (double)Wav2[k];
    sb[tid] = s; __syncthreads();
    for (int off = 128; off > 0; off >>= 1) {
        if (tid < off) sb[tid] += sb[tid + off];
        __syncthreads();
    }
    if (tid == 0) {
        double v = sb[0] + (double)bav2[0];
        w[c] = (float)(1.0 / (1.0 + exp(-v)));
    }
}

__global__ void wsum_kernel(const float* __restrict__ w, const int* __restrict__ sims,
                            double* __restrict__ Wsum) {
    int b = threadIdx.x;
    if (b >= BATCH) return;
    int sb = sims[b];
    double s = 0.0;
    for (int t = 0; t < sb; t++) s += (double)w[t * BATCH + b];
    Wsum[b] = s;
}

// acc init (out + acc_bf in one pass)
__global__ void accinit2_kernel(const float* __restrict__ root,
                                const double* __restrict__ Wsum,
                                float* __restrict__ acc,
                                unsigned short* __restrict__ acc_bf) {
    size_t e = (size_t)blockIdx.x * 256 + threadIdx.x;
    int b = (int)(e >> 20);
    float v = (float)((1.0 + Wsum[b]) * (double)root[e]);
    acc[e] = v;
    acc_bf[e] = f2bf(v);
}

__global__ __launch_bounds__(256)
void corrections_atomic(const float* __restrict__ NS, const float* __restrict__ root,
                        const float* __restrict__ w, const int* __restrict__ sims,
                        const int* __restrict__ idxj, float* __restrict__ acc) {
    int blk = blockIdx.x;                // 0..4799
    int j = blk / NCHAIN, c = blk % NCHAIN;
    int b = c & 15, t = c >> 4;
    if (t >= sims[b]) return;
    float wv = w[c];
    int row = idxj[j * NCHAIN + c];
    const float* ns = NS + ((long)j * NCHAIN + c) * 1024;
    const float* rt = root + (long)row * 1024;
    float* ac = acc + (long)row * 1024;
    for (int h = threadIdx.x; h < 1024; h += 256)
        atomicAdd(&ac[h], wv * (ns[h] - rt[h]));
}

// reconvert touched rows (idempotent across duplicates)
__global__ __launch_bounds__(256)
void reconv_kernel(const float* __restrict__ acc, const int* __restrict__ idxj,
                   unsigned short* __restrict__ acc_bf) {
    int row = idxj[blockIdx.x];          // 0..4799 entries
    const float* src = acc + (long)row * 1024;
    unsigned short* dst = acc_bf + (long)row * 1024;
    for (int h = threadIdx.x; h < 1024; h += 256)
        dst[h] = f2bf(src[h]);
}

// ------------------------------- launch ------------------------------------
extern "C" void kernel_launch(void* const* d_in, const int* in_sizes, int n_in,
                              void* d_out, int out_size, void* d_ws, size_t ws_size,
                              hipStream_t stream) {
    (void)in_sizes; (void)n_in; (void)out_size; (void)ws_size;
    const float* root = (const float*)d_in[0];
    const int*   amask = (const int*)d_in[1];
    const float* Wsc1 = (const float*)d_in[2];  const float* bsc1 = (const float*)d_in[3];
    const float* Wsc2 = (const float*)d_in[4];  const float* bsc2 = (const float*)d_in[5];
    const float* Wp1  = (const float*)d_in[6];  const float* bp1  = (const float*)d_in[7];
    const float* Wp2  = (const float*)d_in[8];  const float* bp2  = (const float*)d_in[9];
    const float* Wt1  = (const float*)d_in[10]; const float* bt1  = (const float*)d_in[11];
    const float* Wt2  = (const float*)d_in[12]; const float* bt2  = (const float*)d_in[13];
    const float* Wav1 = (const float*)d_in[14]; const float* bav1 = (const float*)d_in[15];
    const float* Wav2 = (const float*)d_in[16]; const float* bav2 = (const float*)d_in[17];
    const float* Wg1  = (const float*)d_in[18]; const float* bg1  = (const float*)d_in[19];
    const float* Wg2  = (const float*)d_in[20]; const float* bg2  = (const float*)d_in[21];
    float* out = (float*)d_out;

    // ---- workspace carving (~118 MB) ----
    char* p = (char*)d_ws;
    auto carve = [&](size_t nbytes) -> void* {
        void* r = (void*)p; p += (nbytes + 255) & ~(size_t)255; return r;
    };
    unsigned short* H1big = (unsigned short*)carve((size_t)NCH3 * HDIM * 2);
    float*          Hav   = (float*)carve((size_t)NCHAIN * HDIM * 4);
    float*          NS    = (float*)carve((size_t)3 * NCHAIN * HDIM * 4);
    unsigned short* h_bf  = (unsigned short*)H1big;  // step-9 alias (tenants dead)
    unsigned short* WT3   = (unsigned short*)NS;     // dead before NS written
    unsigned short* WTt1  = (unsigned short*)carve((size_t)1024 * 1024 * 2);  // Wt1[1024:2048]
    unsigned short* WTt2  = (unsigned short*)carve((size_t)1024 * 1024 * 2);
    unsigned short* WTav1 = (unsigned short*)carve((size_t)1024 * 1024 * 2);  // Wav1[1024:2048]
    unsigned short* WTg1  = (unsigned short*)carve((size_t)1024 * 2048 * 2);
    unsigned short* WTg2  = (unsigned short*)carve((size_t)1024 * 1024 * 2);
    float*  rmean  = (float*)carve(BATCH * HDIM * 4);
    float*  Rv_t   = (float*)carve(BATCH * HDIM * 4);
    float*  Rv_av  = (float*)carve(BATCH * HDIM * 4);
    double* rpart  = (double*)carve((size_t)BATCH * 16 * HDIM * 8);
    float*  T1     = (float*)carve(BATCH * HDIM * 4);
    float*  logits = (float*)carve(128 * 4);
    float*  wp2m   = (float*)carve(1040 * 4);
    double* fl64   = (double*)carve((size_t)BATCH * SEQ * 8);
    float*  fl32   = (float*)carve(BATCH * SEQ * 4);
    float*  wbuf   = (float*)carve(NCHAIN * 4);
    double* Wsumd  = (double*)carve(64 * 8);
    int*    sims   = (int*)carve(64 * 4);
    int*    idxj   = (int*)carve(3 * NCHAIN * 4);
    int*    vidx   = (int*)carve(NCHAIN * 4);
    int*    vidx3  = (int*)carve(NCH3 * 4);
    unsigned short* root_bf     = (unsigned short*)carve((size_t)BATCH * SEQ * HDIM * 2);
    unsigned short* acc_bf      = (unsigned short*)carve((size_t)BATCH * SEQ * HDIM * 2);
    unsigned short* root_lo     = acc_bf;   // policy (step 4) dead before acc_bf (step 8)
    unsigned short* mean_cur_bf = (unsigned short*)carve((size_t)NCHAIN * HDIM * 2);
    unsigned short* rmean_bf    = (unsigned short*)carve(BATCH * HDIM * 2);

    const long NTOT8 = (long)BATCH * SEQ * HDIM / 8;
    const int  KBIG = 1 << 30, KMA = 0x7FFFFFFF;

    // 1) weight transposes (+ policy hi/lo triple-stack)
    transpose_bf16<<<dim3(1024 / 32, 1024 / 32), 256, 0, stream>>>(
        Wt1 + (size_t)1024 * 1024, WTt1, 1024, 1024);
    transpose_bf16<<<dim3(1024 / 32, 1024 / 32), 256, 0, stream>>>(Wt2, WTt2, 1024, 1024);
    transpose_bf16<<<dim3(1024 / 32, 1024 / 32), 256, 0, stream>>>(
        Wav1 + (size_t)1024 * 1024, WTav1, 1024, 1024);
    transpose_bf16<<<dim3(2048 / 32, 1024 / 32), 256, 0, stream>>>(Wg1, WTg1, 2048, 1024);
    transpose_bf16<<<dim3(1024 / 32, 1024 / 32), 256, 0, stream>>>(Wg2, WTg2, 1024, 1024);
    transpose_split3<<<dim3(32, 32), 256, 0, stream>>>(Wp1, WT3, 1024, 1024);
    // 1b) root -> bf16 hi+lo once (root_lo aliases acc_bf); vidx3 init
    cvt_split<<<2048, 256, 0, stream>>>(root, root_bf, root_lo, NTOT8);
    vidx3_kernel<<<(NCH3 + 255) / 256, 256, 0, stream>>>(vidx3);
    hipMemsetAsync(Rv_t, 0, BATCH * HDIM * 4, stream);
    hipMemsetAsync(Rv_av, 0, BATCH * HDIM * 4, stream);
    // 2) wp2 means, root mean (two-stage), Rv's
    wp2mean_kernel<<<1025, 256, 0, stream>>>(Wp2, bp2, wp2m);
    rootmean_part<<<256, 256, 0, stream>>>(root, rpart);
    rootmean_fin<<<64, 256, 0, stream>>>(rpart, rmean, rmean_bf);
    rv2_kernel<<<512, 256, 0, stream>>>(rmean, Wt1, Rv_t);     // Wt1 top half
    rv2_kernel<<<512, 256, 0, stream>>>(rmean, Wav1, Rv_av);   // Wav1 top half
    // 3) controller (fp64) -> sims
    ctrl_fc1<<<64, 256, 0, stream>>>(root, Wsc1, bsc1, T1);
    ctrl_fc2<<<80, 256, 0, stream>>>(T1, Wsc2, bsc2, logits);
    sims_kernel<<<1, 64, 0, stream>>>(logits, sims);
    // 4) policy as pipelined K=3072 GEMM ([hi|hi|lo]), 128x256, BK=32
    hipMemsetAsync(fl64, 0, (size_t)BATCH * SEQ * 8, stream);
    gemm_bt<128, 256, 32, 1><<<dim3(4, 128), 512, 0, stream>>>(
        root_bf, 1024, nullptr, root_lo, 1024, nullptr, 2048, 1023,
        WT3, bp1, wp2m, fl64, nullptr, nullptr, nullptr, nullptr, 1024,
        BATCH * SEQ, 1024, 3072, 0);
    flbuild_kernel<<<BATCH * SEQ / 256, 256, 0, stream>>>(fl64, wp2m, amask, fl32);
    // 5) gumbel top-3 (partitionable threefry, unchanged)
    gumbel_kernel<<<NCHAIN, 256, 0, stream>>>(fl32, idxj, vidx);
    // 6) transitions BATCHED over 4800 rows, K=1024 (mean half via Rv_t/Pre)
    gemm_bt<64, 128, 64, 0><<<dim3(8, 75), 512, 0, stream>>>(
        root_bf, 1024, idxj, nullptr, 0, vidx3, KBIG, KMA,
        WTt1, bt1, nullptr, nullptr, Rv_t, nullptr, nullptr, H1big, 1024,
        NCH3, 1024, 1024, 1);
    gemm_bt<64, 128, 64, 0><<<dim3(8, 75), 512, 0, stream>>>(
        H1big, 1024, nullptr, nullptr, 0, nullptr, KBIG, KMA,
        WTt2, bt2, nullptr, nullptr, nullptr, nullptr, NS, nullptr,
        1024, NCH3, 1024, 1024, 0);
    // 6b) exact final per-chain mean for the value path
    meanfinal_kernel<<<NCHAIN * HDIM / 256, 256, 0, stream>>>(
        rmean, NS, root, idxj, mean_cur_bf);
    // 7) action value: K=1024 on mean_cur (rmean half via Rv_av/Pre) -> w
    gemm_bt<64, 128, 64, 0><<<dim3(8, 25), 512, 0, stream>>>(
        mean_cur_bf, 1024, nullptr, nullptr, 0, vidx, KBIG, KMA,
        WTav1, bav1, nullptr, nullptr, Rv_av, nullptr, Hav, nullptr, 1024,
        NCHAIN, 1024, 1024, 1);
    valdot_kernel<<<NCHAIN, 256, 0, stream>>>(Hav, Wav2, bav2, wbuf);
    wsum_kernel<<<1, 64, 0, stream>>>(wbuf, sims, Wsumd);
    // 8) acc (in d_out): init(+bf16) + parallel corrections + touched-row reconv
    accinit2_kernel<<<(BATCH * SEQ * HDIM) / 256, 256, 0, stream>>>(
        root, Wsumd, out, acc_bf);
    corrections_atomic<<<3 * NCHAIN, 256, 0, stream>>>(NS, root, wbuf, sims, idxj, out);
    reconv_kernel<<<NCH3, 256, 0, stream>>>(out, idxj, acc_bf);
    // 9) aggregation (128x256, BK=32, pipelined)
    gemm_bt<128, 256, 32, 0><<<dim3(4, 128), 512, 0, stream>>>(
        root_bf, 1024, nullptr, acc_bf, 1024, nullptr, 1024, KMA,
        WTg1, bg1, nullptr, nullptr, nullptr, nullptr, nullptr, h_bf, 1024,
        BATCH * SEQ, 1024, 2048, 1);
    gemm_bt<128, 256, 32, 0><<<dim3(4, 128), 512, 0, stream>>>(
        h_bf, 1024, nullptr, nullptr, 0, nullptr, KBIG, KMA,
        WTg2, bg2, nullptr, nullptr, nullptr, root, out, nullptr, 1024,
        BATCH * SEQ, 1024, 1024, 0);
}